// Round 9
// baseline (228.188 us; speedup 1.0000x reference)
//
#include <hip/hip_runtime.h>
#include <hip/hip_bf16.h>

#define NN 4096
#define FIN 128
#define FOUT 64
#define NH 8
#define KS 4          // K splits (1024 keys per block)
#define QT 32         // Q rows per block

typedef float f32x4 __attribute__((ext_vector_type(4)));
typedef __bf16 bf16x8 __attribute__((ext_vector_type(8)));
typedef unsigned long long u64;

// ---------------- K0: combined weights Wc[128][80]:
// cols 0..7 = proj[h]@score_src[h]; 8..15 = proj[h]@score_dst[h]; 16..79 = head-folded skip/8
__global__ __launch_bounds__(256) void wc_kernel(
    const float* __restrict__ proj, const float* __restrict__ score_src,
    const float* __restrict__ score_dst, const float* __restrict__ skip_w,
    float* __restrict__ Wc) {
    int idx = blockIdx.x * 256 + threadIdx.x;
    if (idx >= FIN * 80) return;
    int i = idx / 80, c = idx % 80;
    float v = 0.f;
    if (c < 16) {
        int h = c & 7;
        const float* w = (c < 8 ? score_src : score_dst) + h * FOUT;
        const float* p = proj + (size_t)h * FIN * FOUT + (size_t)i * FOUT;
        for (int f = 0; f < FOUT; ++f) v += p[f] * w[f];
    } else {
        int f = c - 16;
        for (int h = 0; h < NH; ++h) v += skip_w[(size_t)(h * FOUT + f) * FIN + i];
        v *= 0.125f;
    }
    Wc[i * 80 + c] = v;
}

// ---------------- K1: x@Wc -> skipm (in d_out), EF (bf16-pair e^d,e^.2d), C12 (e^s,e^.2s), xb.
__global__ __launch_bounds__(256) void scores_kernel(
    const float* __restrict__ x, const float* __restrict__ Wc,
    float* __restrict__ skipm, unsigned* __restrict__ EF, float2* __restrict__ C12,
    __hip_bfloat16* __restrict__ xb_) {
    __shared__ float wcs[FIN][80];     // 40 KB
    __shared__ float xs[16][FIN + 5];
    const int n0 = blockIdx.x * 16;
    const int tid = threadIdx.x;
    for (int i = tid; i < FIN * 80 / 4; i += 256)
        ((float4*)&wcs[0][0])[i] = ((const float4*)Wc)[i];
    const float4* xsrc = (const float4*)(x + (size_t)n0 * FIN);
    for (int i = tid; i < 16 * FIN / 4; i += 256) {
        int r = i >> 5, c4 = i & 31;
        *(float4*)&xs[r][c4 * 4] = xsrc[i];
    }
    __syncthreads();
    const int r = tid & 15;
    const int g = tid >> 4;        // 0..15: 4 skip cols + 1 score col each
    float acc[4];
    float sa = 0.f;
#pragma unroll
    for (int j = 0; j < 4; ++j) acc[j] = 0.f;
#pragma unroll 4
    for (int i = 0; i < FIN; ++i) {
        float xv = xs[r][i];
        float4 p = *(float4*)&wcs[i][16 + g * 4];
        float qv = wcs[i][g];
        acc[0] += xv * p.x; acc[1] += xv * p.y; acc[2] += xv * p.z; acc[3] += xv * p.w;
        sa += xv * qv;
    }
    int n = n0 + r;
#pragma unroll
    for (int j = 0; j < 4; ++j) skipm[(size_t)n * FOUT + g * 4 + j] = acc[j];
    if (g < 8) {
        C12[g * NN + n] = make_float2(expf(sa), expf(0.2f * sa));
    } else {
        __hip_bfloat16 e0 = __float2bfloat16(expf(sa));
        __hip_bfloat16 f0 = __float2bfloat16(expf(0.2f * sa));
        EF[(g - 8) * NN + n] = ((unsigned)*(unsigned short*)&f0 << 16) | (unsigned)*(unsigned short*)&e0;
    }
    {   // x -> bf16: 8 elems per thread
        int row = tid >> 4, col0 = (tid & 15) * 8;
        const float* src = &xs[row][col0];
        bf16x8 b0;
#pragma unroll
        for (int j = 0; j < 8; ++j) b0[j] = (__bf16)src[j];
        *(bf16x8*)((__bf16*)xb_ + (size_t)(n0 + row) * FIN + col0) = b0;
    }
}

// ---------------- K2: Vt[h][f][n] = proj[h]^T @ x^T via bf16 MFMA
__global__ __launch_bounds__(256) void vt_kernel(
    const float* __restrict__ proj, const __hip_bfloat16* __restrict__ xb_,
    __hip_bfloat16* __restrict__ Vt_) {
    __shared__ __bf16 pT[FOUT][FIN + 8];
    const int tid = threadIdx.x;
    const int h = blockIdx.x >> 6;
    const int ng = blockIdx.x & 63;
    const __bf16* xb = (const __bf16*)xb_;
    __bf16* Vt = (__bf16*)Vt_;
    for (int idx = tid; idx < FIN * FOUT; idx += 256) {
        int i = idx >> 6, f = idx & 63;
        pT[f][i] = (__bf16)proj[(size_t)h * FIN * FOUT + idx];
    }
    __syncthreads();
    const int wave = tid >> 6, lane = tid & 63, q = lane >> 4, li = lane & 15;
    const int nb = ng * 64 + wave * 16;
    f32x4 acc[4];
#pragma unroll
    for (int n = 0; n < 4; ++n) acc[n] = (f32x4){0.f, 0.f, 0.f, 0.f};
#pragma unroll
    for (int kt = 0; kt < 4; ++kt) {
        bf16x8 bfrag = *(const bf16x8*)(xb + (size_t)(nb + li) * FIN + kt * 32 + q * 8);
#pragma unroll
        for (int ft = 0; ft < 4; ++ft) {
            bf16x8 afrag = *(const bf16x8*)&pT[ft * 16 + li][kt * 32 + q * 8];
            acc[ft] = __builtin_amdgcn_mfma_f32_16x16x32_bf16(afrag, bfrag, acc[ft], 0, 0, 0);
        }
    }
#pragma unroll
    for (int ft = 0; ft < 4; ++ft)
#pragma unroll
        for (int reg = 0; reg < 4; ++reg)
            Vt[((size_t)h * FOUT + ft * 16 + q * 4 + reg) * NN + nb + li] = (__bf16)acc[ft][reg];
}

// ---------------- K3: attention, head-per-wave, C-level double-buffered pipeline.
// grid = 128 q-tiles x 4 ks = 512 blocks (2/CU); 512 thr = 8 waves = 8 heads.
// Mask built in-kernel from topo (each block ballots its disjoint 32x1024 tile; 67 MB once).
// waves_per_eu(4,4): 128-VGPR budget so the 2x(EF+V) ping-pong (~110 regs) survives.
__attribute__((amdgpu_waves_per_eu(4, 4)))
__global__ __launch_bounds__(512) void attn_kernel(
    const float* __restrict__ topo, const __hip_bfloat16* __restrict__ Vt_,
    const unsigned* __restrict__ EFg, const float2* __restrict__ C12g,
    __hip_bfloat16* __restrict__ accP, float* __restrict__ rsP) {
    __shared__ u64 maskS[QT][17];          // 4.4 KB
    const int tid = threadIdx.x;
    const int h = tid >> 6;                // wave = head
    const int lane = tid & 63, q = lane >> 4, li = lane & 15;
    const int qt = blockIdx.x >> 2, ks = blockIdx.x & 3;
    const int row0 = qt * QT;
    const int kb0 = ks * 1024;

    // ---- build mask from topo tile: 512 u64 words; wave h handles words h*64..h*64+63.
    {
        const float* tpb = topo + (size_t)row0 * NN + kb0;
#pragma unroll 1
        for (int it = 0; it < 64; ++it) {
            int w0 = h * 64 + it;
            float t = tpb[(size_t)(w0 >> 4) * NN + (w0 & 15) * 64 + lane];
            u64 b = __ballot(t > -0.5e9f);
            if (lane == 0) maskS[w0 >> 4][w0 & 15] = b;
        }
    }
    __syncthreads();

    const __bf16* vb = (const __bf16*)Vt_ + (size_t)h * (FOUT * NN) + kb0;
    const unsigned* efb = EFg + (size_t)h * NN + kb0;
    float C1[2], C2[2];
#pragma unroll
    for (int rt = 0; rt < 2; ++rt) {
        float2 c = C12g[(size_t)h * NN + row0 + rt * 16 + li];
        C1[rt] = c.x; C2[rt] = c.y;
    }

    f32x4 acc[2][4];
#pragma unroll
    for (int rt = 0; rt < 2; ++rt)
#pragma unroll
        for (int n = 0; n < 4; ++n) acc[rt][n] = (f32x4){0.f, 0.f, 0.f, 0.f};
    float rs[2] = {0.f, 0.f};

    auto loadc = [&](int kw, uint4& a, uint4& b, bf16x8* v) {
        const unsigned* ep = efb + kw * 32 + q * 8;
        a = *(const uint4*)ep;
        b = *(const uint4*)(ep + 4);
        const __bf16* vp = vb + (size_t)li * NN + kw * 32 + q * 8;
        v[0] = *(const bf16x8*)(vp);
        v[1] = *(const bf16x8*)(vp + 16 * NN);
        v[2] = *(const bf16x8*)(vp + 32 * NN);
        v[3] = *(const bf16x8*)(vp + 48 * NN);
    };
    auto comp = [&](int kt, const uint4& a, const uint4& b, const bf16x8* v) {
        unsigned ew[8] = {a.x, a.y, a.z, a.w, b.x, b.y, b.z, b.w};
#pragma unroll
        for (int rt = 0; rt < 2; ++rt) {
            u64 mw = maskS[rt * 16 + li][kt >> 1];
            unsigned mm = (unsigned)(mw >> ((kt & 1) * 32 + q * 8)) & 0xffu;
            bf16x8 pf;
#pragma unroll
            for (int j = 0; j < 8; ++j) {
                unsigned e = ew[j];
                float E = __uint_as_float(e << 16);
                float F = __uint_as_float(e & 0xffff0000u);
                float pv = fmaxf(C1[rt] * E, C2[rt] * F);
                pv = ((mm >> j) & 1u) ? pv : 0.f;
                rs[rt] += pv;
                pf[j] = (__bf16)pv;
            }
#pragma unroll
            for (int n = 0; n < 4; ++n)
                acc[rt][n] = __builtin_amdgcn_mfma_f32_16x16x32_bf16(pf, v[n], acc[rt][n], 0, 0, 0);
        }
    };

    uint4 a0, b0, a1, b1;
    bf16x8 v0[4], v1[4];
    loadc(0, a0, b0, v0);
#pragma unroll 1
    for (int kt = 0; kt < 32; kt += 2) {
        loadc(kt + 1, a1, b1, v1);
        comp(kt, a0, b0, v0);
        loadc((kt + 2) & 31, a0, b0, v0);   // wraps on last iter; harmless
        comp(kt + 1, a1, b1, v1);
    }

    // epilogue: unnormalized bf16 partials + fp32 row sums
#pragma unroll
    for (int rt = 0; rt < 2; ++rt) {
        float r = rs[rt];
        r += __shfl_xor(r, 16);
        r += __shfl_xor(r, 32);
        if (q == 0) rsP[(size_t)(ks * NH + h) * NN + row0 + rt * 16 + li] = r;
        __hip_bfloat16* ap = accP + ((size_t)(ks * NH + h) * NN + row0 + rt * 16) * 64;
#pragma unroll
        for (int n = 0; n < 4; ++n)
#pragma unroll
            for (int reg = 0; reg < 4; ++reg)
                ap[(q * 4 + reg) * 64 + n * 16 + li] = __float2bfloat16(acc[rt][n][reg]);
    }
}

// ---------------- K4: combine k-split partials + mean heads + skip + LeakyReLU
__global__ __launch_bounds__(256) void combine_kernel(
    const __hip_bfloat16* __restrict__ accP, const float* __restrict__ rsP,
    float* __restrict__ out) {
    int idx = blockIdx.x * 256 + threadIdx.x;      // 262144
    int row = idx >> 6, f = idx & 63;
    float s = 0.f;
#pragma unroll 1
    for (int h = 0; h < NH; ++h) {
        float a = 0.f, r = 0.f;
#pragma unroll
        for (int k = 0; k < KS; ++k) {
            a += __bfloat162float(accP[((size_t)(k * NH + h) * NN + row) * 64 + f]);
            r += rsP[(size_t)(k * NH + h) * NN + row];
        }
        s += a / r;
    }
    float v = s * 0.125f + out[idx];               // out currently holds skipm
    out[idx] = fmaxf(v, 0.2f * v);
}

extern "C" void kernel_launch(void* const* d_in, const int* in_sizes, int n_in,
                              void* d_out, int out_size, void* d_ws, size_t ws_size,
                              hipStream_t stream) {
    (void)in_sizes; (void)n_in; (void)out_size; (void)ws_size;
    const float* x         = (const float*)d_in[0];   // [4096,128]
    const float* topology  = (const float*)d_in[1];   // [4096,4096]
    const float* proj      = (const float*)d_in[2];   // [8,128,64]
    const float* score_src = (const float*)d_in[3];   // [8,64]
    const float* score_dst = (const float*)d_in[4];   // [8,64]
    const float* skip_w    = (const float*)d_in[5];   // [512,128]
    float* out = (float*)d_out;                       // [4096,64]

    char* ws = (char*)d_ws;
    __hip_bfloat16* xb = (__hip_bfloat16*)ws;                 // 1 MB
    __hip_bfloat16* Vt = (__hip_bfloat16*)(ws + 1048576);     // 4 MB
    unsigned* EF  = (unsigned*)(ws + 5242880);                // 128 KB
    float2* C12   = (float2*)(ws + 5373952);                  // 256 KB
    float* Wc     = (float*)(ws + 5636096);                   // 40 KB
    float* rsP    = (float*)(ws + 5677056);                   // 512 KB
    __hip_bfloat16* accP = (__hip_bfloat16*)(ws + 6201344);   // 16 MB (end ~22.2 MB)
    float* skipm = out;   // skip GEMM lives in d_out; combine consumes & overwrites

    wc_kernel<<<40, 256, 0, stream>>>(proj, score_src, score_dst, skip_w, Wc);
    scores_kernel<<<256, 256, 0, stream>>>(x, Wc, skipm, EF, C12, xb);
    vt_kernel<<<512, 256, 0, stream>>>(proj, xb, Vt);
    attn_kernel<<<512, 512, 0, stream>>>(topology, Vt, EF, C12, accP, rsP);
    combine_kernel<<<1024, 256, 0, stream>>>(accP, rsP, out);
}

// Round 10
// 201.100 us; speedup vs baseline: 1.1347x; 1.1347x over previous
//
#include <hip/hip_runtime.h>
#include <hip/hip_bf16.h>

#define NN 4096
#define FIN 128
#define FOUT 64
#define NH 8
#define KS 8          // K splits (512 keys per block)
#define QT 32         // Q rows per block

typedef float f32x4 __attribute__((ext_vector_type(4)));
typedef __bf16 bf16x8 __attribute__((ext_vector_type(8)));
typedef unsigned long long u64;

// ---------------- K0: combined weights Wc[128][80]:
// cols 0..7 = proj[h]@score_src[h]; 8..15 = proj[h]@score_dst[h]; 16..79 = head-folded skip/8
__global__ __launch_bounds__(256) void wc_kernel(
    const float* __restrict__ proj, const float* __restrict__ score_src,
    const float* __restrict__ score_dst, const float* __restrict__ skip_w,
    float* __restrict__ Wc) {
    int idx = blockIdx.x * 256 + threadIdx.x;
    if (idx >= FIN * 80) return;
    int i = idx / 80, c = idx % 80;
    float v = 0.f;
    if (c < 16) {
        int h = c & 7;
        const float* w = (c < 8 ? score_src : score_dst) + h * FOUT;
        const float* p = proj + (size_t)h * FIN * FOUT + (size_t)i * FOUT;
        for (int f = 0; f < FOUT; ++f) v += p[f] * w[f];
    } else {
        int f = c - 16;
        for (int h = 0; h < NH; ++h) v += skip_w[(size_t)(h * FOUT + f) * FIN + i];
        v *= 0.125f;
    }
    Wc[i * 80 + c] = v;
}

// ---------------- K1: x@Wc -> skipm (in d_out), EF (bf16-pair e^d,e^.2d), C12 (e^s,e^.2s), xb.
__global__ __launch_bounds__(256) void scores_kernel(
    const float* __restrict__ x, const float* __restrict__ Wc,
    float* __restrict__ skipm, unsigned* __restrict__ EF, float2* __restrict__ C12,
    __hip_bfloat16* __restrict__ xb_) {
    __shared__ float wcs[FIN][80];     // 40 KB
    __shared__ float xs[16][FIN + 5];
    const int n0 = blockIdx.x * 16;
    const int tid = threadIdx.x;
    for (int i = tid; i < FIN * 80 / 4; i += 256)
        ((float4*)&wcs[0][0])[i] = ((const float4*)Wc)[i];
    const float4* xsrc = (const float4*)(x + (size_t)n0 * FIN);
    for (int i = tid; i < 16 * FIN / 4; i += 256) {
        int r = i >> 5, c4 = i & 31;
        *(float4*)&xs[r][c4 * 4] = xsrc[i];
    }
    __syncthreads();
    const int r = tid & 15;
    const int g = tid >> 4;        // 0..15: 4 skip cols + 1 score col each
    float acc[4];
    float sa = 0.f;
#pragma unroll
    for (int j = 0; j < 4; ++j) acc[j] = 0.f;
#pragma unroll 4
    for (int i = 0; i < FIN; ++i) {
        float xv = xs[r][i];
        float4 p = *(float4*)&wcs[i][16 + g * 4];
        float qv = wcs[i][g];
        acc[0] += xv * p.x; acc[1] += xv * p.y; acc[2] += xv * p.z; acc[3] += xv * p.w;
        sa += xv * qv;
    }
    int n = n0 + r;
#pragma unroll
    for (int j = 0; j < 4; ++j) skipm[(size_t)n * FOUT + g * 4 + j] = acc[j];
    if (g < 8) {
        C12[g * NN + n] = make_float2(expf(sa), expf(0.2f * sa));
    } else {
        __hip_bfloat16 e0 = __float2bfloat16(expf(sa));
        __hip_bfloat16 f0 = __float2bfloat16(expf(0.2f * sa));
        EF[(g - 8) * NN + n] = ((unsigned)*(unsigned short*)&f0 << 16) | (unsigned)*(unsigned short*)&e0;
    }
    {   // x -> bf16: 8 elems per thread
        int row = tid >> 4, col0 = (tid & 15) * 8;
        const float* src = &xs[row][col0];
        bf16x8 b0;
#pragma unroll
        for (int j = 0; j < 8; ++j) b0[j] = (__bf16)src[j];
        *(bf16x8*)((__bf16*)xb_ + (size_t)(n0 + row) * FIN + col0) = b0;
    }
}

// ---------------- K2: Vt[h][f][n] = proj[h]^T @ x^T via bf16 MFMA
__global__ __launch_bounds__(256) void vt_kernel(
    const float* __restrict__ proj, const __hip_bfloat16* __restrict__ xb_,
    __hip_bfloat16* __restrict__ Vt_) {
    __shared__ __bf16 pT[FOUT][FIN + 8];
    const int tid = threadIdx.x;
    const int h = blockIdx.x >> 6;
    const int ng = blockIdx.x & 63;
    const __bf16* xb = (const __bf16*)xb_;
    __bf16* Vt = (__bf16*)Vt_;
    for (int idx = tid; idx < FIN * FOUT; idx += 256) {
        int i = idx >> 6, f = idx & 63;
        pT[f][i] = (__bf16)proj[(size_t)h * FIN * FOUT + idx];
    }
    __syncthreads();
    const int wave = tid >> 6, lane = tid & 63, q = lane >> 4, li = lane & 15;
    const int nb = ng * 64 + wave * 16;
    f32x4 acc[4];
#pragma unroll
    for (int n = 0; n < 4; ++n) acc[n] = (f32x4){0.f, 0.f, 0.f, 0.f};
#pragma unroll
    for (int kt = 0; kt < 4; ++kt) {
        bf16x8 bfrag = *(const bf16x8*)(xb + (size_t)(nb + li) * FIN + kt * 32 + q * 8);
#pragma unroll
        for (int ft = 0; ft < 4; ++ft) {
            bf16x8 afrag = *(const bf16x8*)&pT[ft * 16 + li][kt * 32 + q * 8];
            acc[ft] = __builtin_amdgcn_mfma_f32_16x16x32_bf16(afrag, bfrag, acc[ft], 0, 0, 0);
        }
    }
#pragma unroll
    for (int ft = 0; ft < 4; ++ft)
#pragma unroll
        for (int reg = 0; reg < 4; ++reg)
            Vt[((size_t)h * FOUT + ft * 16 + q * 4 + reg) * NN + nb + li] = (__bf16)acc[ft][reg];
}

// ---------------- K3: attention, head-per-wave, R7 plain K-loop, occupancy-driven.
// grid = 128 q-tiles x 8 ks = 1024 blocks (4/CU target); 512 thr = 8 waves = 8 heads.
// Mask built in-kernel (topo is L3-resident on replays), unroll 4 for load overlap.
// waves_per_eu(5): 102-reg unified budget (usage ~88) -> 5 waves/EU, no spill.
__attribute__((amdgpu_waves_per_eu(5)))
__global__ __launch_bounds__(512) void attn_kernel(
    const float* __restrict__ topo, const __hip_bfloat16* __restrict__ Vt_,
    const unsigned* __restrict__ EFg, const float2* __restrict__ C12g,
    __hip_bfloat16* __restrict__ accP, float* __restrict__ rsP) {
    __shared__ u64 maskS[QT][9];           // 2.3 KB
    const int tid = threadIdx.x;
    const int h = tid >> 6;                // wave = head
    const int lane = tid & 63, q = lane >> 4, li = lane & 15;
    const int qt = blockIdx.x >> 3, ks = blockIdx.x & 7;
    const int row0 = qt * QT;
    const int kb0 = ks * 512;

    // ---- build mask from topo tile (32 rows x 512 cols = 256 u64 words).
    // wave h: words h*32..h*32+31; word w: row=w>>3, seg=w&7. unroll 4 => 4 loads in flight.
    {
        const float* tpb = topo + (size_t)row0 * NN + kb0;
#pragma unroll 1
        for (int it = 0; it < 32; it += 4) {
            int w0 = h * 32 + it;
            float t0 = tpb[(size_t)((w0 + 0) >> 3) * NN + ((w0 + 0) & 7) * 64 + lane];
            float t1 = tpb[(size_t)((w0 + 1) >> 3) * NN + ((w0 + 1) & 7) * 64 + lane];
            float t2 = tpb[(size_t)((w0 + 2) >> 3) * NN + ((w0 + 2) & 7) * 64 + lane];
            float t3 = tpb[(size_t)((w0 + 3) >> 3) * NN + ((w0 + 3) & 7) * 64 + lane];
            u64 b0 = __ballot(t0 > -0.5e9f);
            u64 b1 = __ballot(t1 > -0.5e9f);
            u64 b2 = __ballot(t2 > -0.5e9f);
            u64 b3 = __ballot(t3 > -0.5e9f);
            if (lane == 0) {
                maskS[(w0 + 0) >> 3][(w0 + 0) & 7] = b0;
                maskS[(w0 + 1) >> 3][(w0 + 1) & 7] = b1;
                maskS[(w0 + 2) >> 3][(w0 + 2) & 7] = b2;
                maskS[(w0 + 3) >> 3][(w0 + 3) & 7] = b3;
            }
        }
    }
    __syncthreads();

    const __bf16* vb = (const __bf16*)Vt_ + (size_t)h * (FOUT * NN) + kb0;
    const unsigned* efb = EFg + (size_t)h * NN + kb0;
    float C1[2], C2[2];
#pragma unroll
    for (int rt = 0; rt < 2; ++rt) {
        float2 c = C12g[(size_t)h * NN + row0 + rt * 16 + li];
        C1[rt] = c.x; C2[rt] = c.y;
    }

    f32x4 acc[2][4];                       // 32 AGPRs
#pragma unroll
    for (int rt = 0; rt < 2; ++rt)
#pragma unroll
        for (int n = 0; n < 4; ++n) acc[rt][n] = (f32x4){0.f, 0.f, 0.f, 0.f};
    float rs[2] = {0.f, 0.f};

#pragma unroll 1
    for (int kt = 0; kt < 16; ++kt) {      // 32-key chunks
        const unsigned* ep = efb + kt * 32 + q * 8;
        uint4 ea = *(const uint4*)ep;
        uint4 eb = *(const uint4*)(ep + 4);
        bf16x8 vf[4];
#pragma unroll
        for (int n = 0; n < 4; ++n)
            vf[n] = *(const bf16x8*)(vb + (size_t)(n * 16 + li) * NN + kt * 32 + q * 8);
        unsigned ew[8] = {ea.x, ea.y, ea.z, ea.w, eb.x, eb.y, eb.z, eb.w};
#pragma unroll
        for (int rt = 0; rt < 2; ++rt) {
            u64 mw = maskS[rt * 16 + li][kt >> 1];
            unsigned mm = (unsigned)(mw >> ((kt & 1) * 32 + q * 8)) & 0xffu;
            bf16x8 pf;
#pragma unroll
            for (int j = 0; j < 8; ++j) {
                unsigned e = ew[j];
                float E = __uint_as_float(e << 16);
                float F = __uint_as_float(e & 0xffff0000u);
                float pv = fmaxf(C1[rt] * E, C2[rt] * F);
                pv = ((mm >> j) & 1u) ? pv : 0.f;
                rs[rt] += pv;
                pf[j] = (__bf16)pv;
            }
#pragma unroll
            for (int n = 0; n < 4; ++n)
                acc[rt][n] = __builtin_amdgcn_mfma_f32_16x16x32_bf16(pf, vf[n], acc[rt][n], 0, 0, 0);
        }
    }

    // epilogue: unnormalized bf16 partials + fp32 row sums
#pragma unroll
    for (int rt = 0; rt < 2; ++rt) {
        float r = rs[rt];
        r += __shfl_xor(r, 16);
        r += __shfl_xor(r, 32);
        if (q == 0) rsP[(size_t)(ks * NH + h) * NN + row0 + rt * 16 + li] = r;
        __hip_bfloat16* ap = accP + ((size_t)(ks * NH + h) * NN + row0 + rt * 16) * 64;
#pragma unroll
        for (int n = 0; n < 4; ++n)
#pragma unroll
            for (int reg = 0; reg < 4; ++reg)
                ap[(q * 4 + reg) * 64 + n * 16 + li] = __float2bfloat16(acc[rt][n][reg]);
    }
}

// ---------------- K4: combine k-split partials + mean heads + skip + LeakyReLU
__global__ __launch_bounds__(256) void combine_kernel(
    const __hip_bfloat16* __restrict__ accP, const float* __restrict__ rsP,
    float* __restrict__ out) {
    int idx = blockIdx.x * 256 + threadIdx.x;      // 262144
    int row = idx >> 6, f = idx & 63;
    float s = 0.f;
#pragma unroll 1
    for (int h = 0; h < NH; ++h) {
        float a = 0.f, r = 0.f;
#pragma unroll
        for (int k = 0; k < KS; ++k) {
            a += __bfloat162float(accP[((size_t)(k * NH + h) * NN + row) * 64 + f]);
            r += rsP[(size_t)(k * NH + h) * NN + row];
        }
        s += a / r;
    }
    float v = s * 0.125f + out[idx];               // out currently holds skipm
    out[idx] = fmaxf(v, 0.2f * v);
}

extern "C" void kernel_launch(void* const* d_in, const int* in_sizes, int n_in,
                              void* d_out, int out_size, void* d_ws, size_t ws_size,
                              hipStream_t stream) {
    (void)in_sizes; (void)n_in; (void)out_size; (void)ws_size;
    const float* x         = (const float*)d_in[0];   // [4096,128]
    const float* topology  = (const float*)d_in[1];   // [4096,4096]
    const float* proj      = (const float*)d_in[2];   // [8,128,64]
    const float* score_src = (const float*)d_in[3];   // [8,64]
    const float* score_dst = (const float*)d_in[4];   // [8,64]
    const float* skip_w    = (const float*)d_in[5];   // [512,128]
    float* out = (float*)d_out;                       // [4096,64]

    char* ws = (char*)d_ws;
    __hip_bfloat16* xb = (__hip_bfloat16*)ws;                 // 1 MB
    __hip_bfloat16* Vt = (__hip_bfloat16*)(ws + 1048576);     // 4 MB
    unsigned* EF  = (unsigned*)(ws + 5242880);                // 128 KB
    float2* C12   = (float2*)(ws + 5373952);                  // 256 KB
    float* Wc     = (float*)(ws + 5636096);                   // 40 KB
    float* rsP    = (float*)(ws + 5677056);                   // 1 MB
    __hip_bfloat16* accP = (__hip_bfloat16*)(ws + 6725632);   // 32 MB (end ~38.4 MB)
    float* skipm = out;   // skip GEMM lives in d_out; combine consumes & overwrites

    wc_kernel<<<40, 256, 0, stream>>>(proj, score_src, score_dst, skip_w, Wc);
    scores_kernel<<<256, 256, 0, stream>>>(x, Wc, skipm, EF, C12, xb);
    vt_kernel<<<512, 256, 0, stream>>>(proj, xb, Vt);
    attn_kernel<<<1024, 512, 0, stream>>>(topology, Vt, EF, C12, accP, rsP);
    combine_kernel<<<1024, 256, 0, stream>>>(accP, rsP, out);
}

// Round 11
// 187.481 us; speedup vs baseline: 1.2171x; 1.0726x over previous
//
#include <hip/hip_runtime.h>
#include <hip/hip_bf16.h>

#define NN 4096
#define FIN 128
#define FOUT 64
#define NH 8
#define KS 8          // K splits (512 keys per block)
#define QT 32         // Q rows per block

typedef float f32x4 __attribute__((ext_vector_type(4)));
typedef __bf16 bf16x8 __attribute__((ext_vector_type(8)));
typedef unsigned long long u64;

// ---------------- K0: combined weights Wc[128][80]
__global__ __launch_bounds__(256) void wc_kernel(
    const float* __restrict__ proj, const float* __restrict__ score_src,
    const float* __restrict__ score_dst, const float* __restrict__ skip_w,
    float* __restrict__ Wc) {
    int idx = blockIdx.x * 256 + threadIdx.x;
    if (idx >= FIN * 80) return;
    int i = idx / 80, c = idx % 80;
    float v = 0.f;
    if (c < 16) {
        int h = c & 7;
        const float* w = (c < 8 ? score_src : score_dst) + h * FOUT;
        const float* p = proj + (size_t)h * FIN * FOUT + (size_t)i * FOUT;
        for (int f = 0; f < FOUT; ++f) v += p[f] * w[f];
    } else {
        int f = c - 16;
        for (int h = 0; h < NH; ++h) v += skip_w[(size_t)(h * FOUT + f) * FIN + i];
        v *= 0.125f;
    }
    Wc[i * 80 + c] = v;
}

// ---------------- K1: x@Wc -> skipm (in d_out), EF, C12, xb
__global__ __launch_bounds__(256) void scores_kernel(
    const float* __restrict__ x, const float* __restrict__ Wc,
    float* __restrict__ skipm, unsigned* __restrict__ EF, float2* __restrict__ C12,
    __hip_bfloat16* __restrict__ xb_) {
    __shared__ float wcs[FIN][80];
    __shared__ float xs[16][FIN + 5];
    const int n0 = blockIdx.x * 16;
    const int tid = threadIdx.x;
    for (int i = tid; i < FIN * 80 / 4; i += 256)
        ((float4*)&wcs[0][0])[i] = ((const float4*)Wc)[i];
    const float4* xsrc = (const float4*)(x + (size_t)n0 * FIN);
    for (int i = tid; i < 16 * FIN / 4; i += 256) {
        int r = i >> 5, c4 = i & 31;
        *(float4*)&xs[r][c4 * 4] = xsrc[i];
    }
    __syncthreads();
    const int r = tid & 15;
    const int g = tid >> 4;
    float acc[4];
    float sa = 0.f;
#pragma unroll
    for (int j = 0; j < 4; ++j) acc[j] = 0.f;
#pragma unroll 4
    for (int i = 0; i < FIN; ++i) {
        float xv = xs[r][i];
        float4 p = *(float4*)&wcs[i][16 + g * 4];
        float qv = wcs[i][g];
        acc[0] += xv * p.x; acc[1] += xv * p.y; acc[2] += xv * p.z; acc[3] += xv * p.w;
        sa += xv * qv;
    }
    int n = n0 + r;
#pragma unroll
    for (int j = 0; j < 4; ++j) skipm[(size_t)n * FOUT + g * 4 + j] = acc[j];
    if (g < 8) {
        C12[g * NN + n] = make_float2(expf(sa), expf(0.2f * sa));
    } else {
        __hip_bfloat16 e0 = __float2bfloat16(expf(sa));
        __hip_bfloat16 f0 = __float2bfloat16(expf(0.2f * sa));
        EF[(g - 8) * NN + n] = ((unsigned)*(unsigned short*)&f0 << 16) | (unsigned)*(unsigned short*)&e0;
    }
    {
        int row = tid >> 4, col0 = (tid & 15) * 8;
        const float* src = &xs[row][col0];
        bf16x8 b0;
#pragma unroll
        for (int j = 0; j < 8; ++j) b0[j] = (__bf16)src[j];
        *(bf16x8*)((__bf16*)xb_ + (size_t)(n0 + row) * FIN + col0) = b0;
    }
}

// ---------------- K2: Vt[h][f][n] = proj[h]^T @ x^T via bf16 MFMA
__global__ __launch_bounds__(256) void vt_kernel(
    const float* __restrict__ proj, const __hip_bfloat16* __restrict__ xb_,
    __hip_bfloat16* __restrict__ Vt_) {
    __shared__ __bf16 pT[FOUT][FIN + 8];
    const int tid = threadIdx.x;
    const int h = blockIdx.x >> 6;
    const int ng = blockIdx.x & 63;
    const __bf16* xb = (const __bf16*)xb_;
    __bf16* Vt = (__bf16*)Vt_;
    for (int idx = tid; idx < FIN * FOUT; idx += 256) {
        int i = idx >> 6, f = idx & 63;
        pT[f][i] = (__bf16)proj[(size_t)h * FIN * FOUT + idx];
    }
    __syncthreads();
    const int wave = tid >> 6, lane = tid & 63, q = lane >> 4, li = lane & 15;
    const int nb = ng * 64 + wave * 16;
    f32x4 acc[4];
#pragma unroll
    for (int n = 0; n < 4; ++n) acc[n] = (f32x4){0.f, 0.f, 0.f, 0.f};
#pragma unroll
    for (int kt = 0; kt < 4; ++kt) {
        bf16x8 bfrag = *(const bf16x8*)(xb + (size_t)(nb + li) * FIN + kt * 32 + q * 8);
#pragma unroll
        for (int ft = 0; ft < 4; ++ft) {
            bf16x8 afrag = *(const bf16x8*)&pT[ft * 16 + li][kt * 32 + q * 8];
            acc[ft] = __builtin_amdgcn_mfma_f32_16x16x32_bf16(afrag, bfrag, acc[ft], 0, 0, 0);
        }
    }
#pragma unroll
    for (int ft = 0; ft < 4; ++ft)
#pragma unroll
        for (int reg = 0; reg < 4; ++reg)
            Vt[((size_t)h * FOUT + ft * 16 + q * 4 + reg) * NN + nb + li] = (__bf16)acc[ft][reg];
}

// ---------------- K3: topology -> bitmask (streaming)
__global__ __launch_bounds__(256) void mask_kernel(
    const float* __restrict__ topo, u64* __restrict__ mb) {
    const int w = blockIdx.x * 4 + (threadIdx.x >> 6);
    const int lane = threadIdx.x & 63;
    size_t base = (size_t)w * 32;
#pragma unroll 4
    for (int it = 0; it < 32; ++it) {
        size_t u = base + it;
        float t = topo[u * 64 + lane];
        u64 b = __ballot(t > -0.5e9f);
        if (lane == 0) mb[u] = b;
    }
}

// ---------------- K4: attention, head-per-wave, wave-private LDS-DMA double buffer.
// grid = 128 qt x 8 ks x 2 head-halves = 2048 blocks x 256 thr (4 waves = 4 heads).
// No barriers in K-loop: DMA completion tracked by the wave's own vmcnt.
// Per chunk: EF loads (pinned first) -> 4 DMA for next chunk -> s_waitcnt vmcnt(4)
// (retires current chunk's DMAs + EF; next chunk's DMAs stay in flight) -> ds_read.
// Separate vA/vB shared objects so the LDS-DMA hazard pass doesn't emit vmcnt(0).
__attribute__((amdgpu_waves_per_eu(4)))
__global__ __launch_bounds__(256) void attn_kernel(
    const u64* __restrict__ maskbits, const __hip_bfloat16* __restrict__ Vt_,
    const unsigned* __restrict__ EFg, const float2* __restrict__ C12g,
    __hip_bfloat16* __restrict__ accP, float* __restrict__ rsP) {
    __shared__ u64 maskS[QT][9];          // 2.3 KB
    __shared__ char vA[4][4096];          // 16 KB: per-wave buffer A
    __shared__ char vB[4][4096];          // 16 KB: per-wave buffer B
    const int tid = threadIdx.x;
    const int w = tid >> 6;
    const int lane = tid & 63, q = lane >> 4, li = lane & 15;
    const int qt = blockIdx.x >> 4, ks = (blockIdx.x >> 1) & 7, hb = blockIdx.x & 1;
    const int h = hb * 4 + w;
    const int row0 = qt * QT;
    const int kb0 = ks * 512;

    // DMA lane geometry: call c covers f-rows c*16..c*16+15; lane l -> row r=l>>2,
    // slot s=l&3 holding global seg (s - (r>>1))&3  => reader slot (q+(li>>1))&3.
    const int r_ = lane >> 2;
    const int sg = ((lane & 3) - (r_ >> 1)) & 3;
    const size_t laneoff = (size_t)r_ * NN + sg * 8;            // bf16 units
    const int rdoff = li * 64 + ((q + (li >> 1)) & 3) * 16;     // bytes

    const __bf16* vb = (const __bf16*)Vt_ + (size_t)h * (FOUT * NN) + kb0;
    const unsigned* efb = EFg + (size_t)h * NN + kb0;

#define DMA_TILE(DST, KT) do {                                                     \
    _Pragma("unroll")                                                              \
    for (int c = 0; c < 4; ++c) {                                                  \
        const __bf16* g_ = vb + (size_t)c * (16 * NN) + (KT) * 32 + laneoff;       \
        __builtin_amdgcn_global_load_lds(                                          \
            (const __attribute__((address_space(1))) void*)g_,                     \
            (__attribute__((address_space(3))) void*)&DST[w][c * 1024], 16, 0, 0); \
    }                                                                              \
} while (0)

    DMA_TILE(vA, 0);
    { int rr = tid >> 3, wd = tid & 7;    // 256 words, one per thread
      maskS[rr][wd] = maskbits[(size_t)(row0 + rr) * 64 + ks * 8 + wd]; }
    __syncthreads();                      // also drains DMA(0)

    float C1[2], C2[2];
#pragma unroll
    for (int rt = 0; rt < 2; ++rt) {
        float2 c = C12g[(size_t)h * NN + row0 + rt * 16 + li];
        C1[rt] = c.x; C2[rt] = c.y;
    }
    f32x4 acc[2][4];
#pragma unroll
    for (int rt = 0; rt < 2; ++rt)
#pragma unroll
        for (int n = 0; n < 4; ++n) acc[rt][n] = (f32x4){0.f, 0.f, 0.f, 0.f};
    float rs[2] = {0.f, 0.f};

#define CHUNK_BODY(SRC, DSTN, KT) do {                                                        \
    const unsigned* ep_ = efb + (KT) * 32 + q * 8;                                            \
    uint4 ea_ = *(const uint4*)ep_;                                                           \
    uint4 eb_ = *(const uint4*)(ep_ + 4);                                                     \
    asm volatile("" ::: "memory");             /* pin EF loads before the DMA */              \
    DMA_TILE(DSTN, ((KT) + 1) & 15);                                                          \
    asm volatile("s_waitcnt vmcnt(4)" ::: "memory");                                          \
    bf16x8 vf_[4];                                                                            \
    _Pragma("unroll")                                                                         \
    for (int n = 0; n < 4; ++n)                                                               \
        vf_[n] = *(const bf16x8*)&SRC[w][n * 1024 + rdoff];                                   \
    unsigned ew_[8] = {ea_.x, ea_.y, ea_.z, ea_.w, eb_.x, eb_.y, eb_.z, eb_.w};               \
    _Pragma("unroll")                                                                         \
    for (int rt = 0; rt < 2; ++rt) {                                                          \
        u64 mw_ = maskS[rt * 16 + li][(KT) >> 1];                                             \
        unsigned mm_ = (unsigned)(mw_ >> (((KT) & 1) * 32 + q * 8)) & 0xffu;                  \
        bf16x8 pf_;                                                                           \
        _Pragma("unroll")                                                                     \
        for (int j = 0; j < 8; ++j) {                                                         \
            unsigned e_ = ew_[j];                                                             \
            float E_ = __uint_as_float(e_ << 16);                                             \
            float F_ = __uint_as_float(e_ & 0xffff0000u);                                     \
            float pv_ = fmaxf(C1[rt] * E_, C2[rt] * F_);                                      \
            pv_ = ((mm_ >> j) & 1u) ? pv_ : 0.f;                                              \
            rs[rt] += pv_;                                                                    \
            pf_[j] = (__bf16)pv_;                                                             \
        }                                                                                     \
        _Pragma("unroll")                                                                     \
        for (int n = 0; n < 4; ++n)                                                           \
            acc[rt][n] = __builtin_amdgcn_mfma_f32_16x16x32_bf16(pf_, vf_[n], acc[rt][n],     \
                                                                 0, 0, 0);                    \
    }                                                                                         \
} while (0)

#pragma unroll 1
    for (int kt = 0; kt < 16; kt += 2) {
        CHUNK_BODY(vA, vB, kt);
        CHUNK_BODY(vB, vA, kt + 1);
    }
#undef CHUNK_BODY
#undef DMA_TILE

    // epilogue: unnormalized bf16 partials + fp32 row sums
#pragma unroll
    for (int rt = 0; rt < 2; ++rt) {
        float r = rs[rt];
        r += __shfl_xor(r, 16);
        r += __shfl_xor(r, 32);
        if (q == 0) rsP[(size_t)(ks * NH + h) * NN + row0 + rt * 16 + li] = r;
        __hip_bfloat16* ap = accP + ((size_t)(ks * NH + h) * NN + row0 + rt * 16) * 64;
#pragma unroll
        for (int n = 0; n < 4; ++n)
#pragma unroll
            for (int reg = 0; reg < 4; ++reg)
                ap[(q * 4 + reg) * 64 + n * 16 + li] = __float2bfloat16(acc[rt][n][reg]);
    }
}

// ---------------- K5: combine k-split partials + mean heads + skip + LeakyReLU
__global__ __launch_bounds__(256) void combine_kernel(
    const __hip_bfloat16* __restrict__ accP, const float* __restrict__ rsP,
    float* __restrict__ out) {
    int idx = blockIdx.x * 256 + threadIdx.x;      // 262144
    int row = idx >> 6, f = idx & 63;
    float s = 0.f;
#pragma unroll 1
    for (int h = 0; h < NH; ++h) {
        float a = 0.f, r = 0.f;
#pragma unroll
        for (int k = 0; k < KS; ++k) {
            a += __bfloat162float(accP[((size_t)(k * NH + h) * NN + row) * 64 + f]);
            r += rsP[(size_t)(k * NH + h) * NN + row];
        }
        s += a / r;
    }
    float v = s * 0.125f + out[idx];               // out currently holds skipm
    out[idx] = fmaxf(v, 0.2f * v);
}

extern "C" void kernel_launch(void* const* d_in, const int* in_sizes, int n_in,
                              void* d_out, int out_size, void* d_ws, size_t ws_size,
                              hipStream_t stream) {
    (void)in_sizes; (void)n_in; (void)out_size; (void)ws_size;
    const float* x         = (const float*)d_in[0];   // [4096,128]
    const float* topology  = (const float*)d_in[1];   // [4096,4096]
    const float* proj      = (const float*)d_in[2];   // [8,128,64]
    const float* score_src = (const float*)d_in[3];   // [8,64]
    const float* score_dst = (const float*)d_in[4];   // [8,64]
    const float* skip_w    = (const float*)d_in[5];   // [512,128]
    float* out = (float*)d_out;                       // [4096,64]

    char* ws = (char*)d_ws;
    __hip_bfloat16* xb = (__hip_bfloat16*)ws;                 // 1 MB
    __hip_bfloat16* Vt = (__hip_bfloat16*)(ws + 1048576);     // 4 MB
    unsigned* EF  = (unsigned*)(ws + 5242880);                // 128 KB
    float2* C12   = (float2*)(ws + 5373952);                  // 256 KB
    float* Wc     = (float*)(ws + 5636096);                   // 40 KB
    u64* maskbits = (u64*)(ws + 5677056);                     // 2 MB
    float* rsP    = (float*)(ws + 7774208);                   // 1 MB
    __hip_bfloat16* accP = (__hip_bfloat16*)(ws + 8822784);   // 32 MB (end ~40.8 MB)
    float* skipm = out;   // skip GEMM lives in d_out; combine consumes & overwrites

    wc_kernel<<<40, 256, 0, stream>>>(proj, score_src, score_dst, skip_w, Wc);
    scores_kernel<<<256, 256, 0, stream>>>(x, Wc, skipm, EF, C12, xb);
    vt_kernel<<<512, 256, 0, stream>>>(proj, xb, Vt);
    mask_kernel<<<2048, 256, 0, stream>>>(topology, maskbits);
    attn_kernel<<<2048, 256, 0, stream>>>(maskbits, Vt, EF, C12, accP, rsP);
    combine_kernel<<<1024, 256, 0, stream>>>(accP, rsP, out);
}